// Round 7
// baseline (909.995 us; speedup 1.0000x reference)
//
#include <hip/hip_runtime.h>
#include <cstddef>

#define TT 256
#define HH 128
#define EST 132    // E row stride: b128 reads spread 8 dwords on every bank = balanced
#define SCPS 260   // scp row stride: 16B-aligned rows, banks balanced

__device__ __forceinline__ float rdlane(float v, int l) {
  return __int_as_float(__builtin_amdgcn_readlane(__float_as_int(v), l));
}
// DPP lane moves (VALU pipe; replaces ds_swizzle on LDS pipe). Verified R6.
template<int CTRL>
__device__ __forceinline__ float dpp_mv(float x) {
  return __int_as_float(
      __builtin_amdgcn_mov_dpp(__float_as_int(x), CTRL, 0xF, 0xF, true));
}
// quad_perm [1,0,3,2]=0xB1, [2,3,0,1]=0x4E, row_ror:4=0x124, row_ror:8=0x128
__device__ __forceinline__ float wave_max64(float x) {
  x = fmaxf(x, dpp_mv<0xB1>(x));
  x = fmaxf(x, dpp_mv<0x4E>(x));
  x = fmaxf(x, dpp_mv<0x124>(x));
  x = fmaxf(x, dpp_mv<0x128>(x));
  x = fmaxf(x, __shfl_xor(x, 16));
  x = fmaxf(x, __shfl_xor(x, 32));
  return x;
}
__device__ __forceinline__ float wave_sum64(float x) {
  x += dpp_mv<0xB1>(x);
  x += dpp_mv<0x4E>(x);
  x += dpp_mv<0x124>(x);
  x += dpp_mv<0x128>(x);
  x += __shfl_xor(x, 16);
  x += __shfl_xor(x, 32);
  return x;
}
__device__ __forceinline__ float fast_sigmoid(float x) {
  const float L2E = 1.4426950408889634f;
  float y = __builtin_amdgcn_exp2f(-x * L2E);
  return __builtin_amdgcn_rcpf(1.0f + y);
}
__device__ __forceinline__ float fast_tanh(float x) {
  const float C2 = 2.8853900817779268f;   // 2*log2(e)
  float y = __builtin_amdgcn_exp2f(x * C2);
  return 1.0f - 2.0f * __builtin_amdgcn_rcpf(1.0f + y);
}

// One workgroup per batch element; 1024 threads = 16 waves (4/SIMD).
// Ledger: R0=752 | R1 1024thr=830 (AGPR split + reduce redundancy) | R2 ds_add=1222 |
// R4 reorder=flat | R5 pk-fma=793 | R6 DPP=flat BUT +7.3M bank conflicts at zero cost
// => LDS pipe has slack; VALU ~30%/SIMD; kernel is LATENCY-bound at 2 waves/SIMD.
// R7 = 1024 threads with R1's two taxes removed:
//  (1) Wr NOT register-resident: streamed from global (L2-resident, addresses
//      loop-invariant) in two 16xfloat2 batches issued ~200+cy before use.
//      Persistent regs ~55 -> fits the 128-reg/wave budget in real VGPRs.
//  (2) Apre h-fetch: 1 ds_read_b32 + rdlane (R0-prologue pattern, NOT R5's
//      strided b64). Softmax de-replicated to wave 4 only. C uses 8-group
//      conflict-free layout (bank quad 4*jq). D: 8 k/wave, scp[16] rows.
// R2 lesson: no LDS atomics in the loop. R5 lesson: no lane-strided b64 of hbuf.
__global__ __attribute__((amdgpu_flat_work_group_size(1024, 1024),
                          amdgpu_waves_per_eu(4, 4)))
void decoder_kernel(const float* __restrict__ x,
                    const float* __restrict__ enc_output,
                    const float* __restrict__ h0,
                    const float* __restrict__ c0,
                    const float* __restrict__ W1,
                    const float* __restrict__ W2,
                    const float* __restrict__ V,
                    const float* __restrict__ Wk,
                    const float* __restrict__ Wr,
                    const float* __restrict__ bias,
                    float* __restrict__ out)
{
  __shared__ float E[TT * EST];      // 135168 B : exp2(C2 * enc_proj)
  __shared__ float zpart[4 * 512];   // 8192 B   : h@Wr k-quarter partials
  __shared__ float scp[16 * SCPS];   // 16640 B  : phase-D partials [koctet][t]
  __shared__ float hbuf[HH];         // 512 B
  __shared__ float xlds[2 * TT];     // 2048 B   : x pairs (ptr lookup)
  // total 162560 B <= 160 KiB

  const int u    = threadIdx.x;
  const int b    = blockIdx.x;
  const int lane = u & 63;
  const int w    = u >> 6;           // wave 0..15 (owns k in [8w,8w+8) for C/D)
  const float C2  = 2.8853900817779268f;
  const float L2E = 1.4426950408889634f;

  // ---------------- P0: enc_proj = enc_output[b] @ W1 -> E (raw) ----------------
  {
    const float* encb = enc_output + (size_t)b * TT * HH;
    const int tsub = u >> 4;          // 0..63
    const int ks   = (u & 15) * 8;
    for (int p = 0; p < 4; ++p) {
      const int tt = p * 64 + tsub;
      float4 a0 = {0.f, 0.f, 0.f, 0.f};
      float4 a1 = {0.f, 0.f, 0.f, 0.f};
      const float4* er4 = (const float4*)(encb + tt * HH);
      for (int j4 = 0; j4 < 32; ++j4) {
        const float4 ev = er4[j4];
        const float* w1p = W1 + (j4 * 4) * HH + ks;
        float4 wa, wb;
        wa = *(const float4*)(w1p + 0 * HH); wb = *(const float4*)(w1p + 0 * HH + 4);
        a0.x += ev.x * wa.x; a0.y += ev.x * wa.y; a0.z += ev.x * wa.z; a0.w += ev.x * wa.w;
        a1.x += ev.x * wb.x; a1.y += ev.x * wb.y; a1.z += ev.x * wb.z; a1.w += ev.x * wb.w;
        wa = *(const float4*)(w1p + 1 * HH); wb = *(const float4*)(w1p + 1 * HH + 4);
        a0.x += ev.y * wa.x; a0.y += ev.y * wa.y; a0.z += ev.y * wa.z; a0.w += ev.y * wa.w;
        a1.x += ev.y * wb.x; a1.y += ev.y * wb.y; a1.z += ev.y * wb.z; a1.w += ev.y * wb.w;
        wa = *(const float4*)(w1p + 2 * HH); wb = *(const float4*)(w1p + 2 * HH + 4);
        a0.x += ev.z * wa.x; a0.y += ev.z * wa.y; a0.z += ev.z * wa.z; a0.w += ev.z * wa.w;
        a1.x += ev.z * wb.x; a1.y += ev.z * wb.y; a1.z += ev.z * wb.z; a1.w += ev.z * wb.w;
        wa = *(const float4*)(w1p + 3 * HH); wb = *(const float4*)(w1p + 3 * HH + 4);
        a0.x += ev.w * wa.x; a0.y += ev.w * wa.y; a0.z += ev.w * wa.z; a0.w += ev.w * wa.w;
        a1.x += ev.w * wb.x; a1.y += ev.w * wb.y; a1.z += ev.w * wb.z; a1.w += ev.w * wb.w;
      }
      *(float4*)(&E[tt * EST + ks])     = a0;
      *(float4*)(&E[tt * EST + ks + 4]) = a1;
    }
    if (u < 2 * TT) xlds[u] = x[b * (TT * 2) + u];
  }

  // ---------------- persistent registers ----------------
  // Apre: thread (kq = u>>8, cs2 = u&255) owns cols 2cs2..2cs2+1, k in [32kq,+32)
  const int kq  = u >> 8;            // wave-uniform (w>>2)
  const int cs2 = u & 255;
  const float* wrp = Wr + (size_t)(32 * kq) * 512 + 2 * cs2;   // row stride 512
  // Gates: lanes 0..31 of waves 0..3 own unit m = 32w+lane (SIMD-balanced)
  const int m = 32 * (w & 3) + (lane & 31);
  float wkA[4], wkB[4], bbg[4];
  #pragma unroll
  for (int gg = 0; gg < 4; ++gg) {
    wkA[gg] = Wk[gg * HH + m];
    wkB[gg] = Wk[512 + gg * HH + m];
    bbg[gg] = bias[gg * HH + m];
  }
  float c = c0[b * HH + m];
  // Phase C (wave-local k-octet): lane -> kk = lane&7, group jq = lane>>3.
  // Group jq owns j in {4jq + 32ii + cc} (bank-quad 4jq -> conflict-free b128).
  const int kk = lane & 7;
  const int jq = lane >> 3;
  float w2loc[16];                   // [4*ii+cc] = W2[4jq+32ii+cc][8w+kk]
  #pragma unroll
  for (int ii = 0; ii < 4; ++ii)
    #pragma unroll
    for (int cc = 0; cc < 4; ++cc)
      w2loc[4 * ii + cc] = W2[(4 * jq + 32 * ii + cc) * HH + 8 * w + kk];
  // Phase D: v2 for k = 8w+i (lane i holds kk=i)
  const float v2r = -2.0f * V[8 * w + kk];
  float ptr0 = 1.0f, ptr1 = 1.0f;
  float svr;
  {
    float v = V[lane] + V[64 + lane];
    svr = wave_sum64(v);
  }

  __syncthreads();   // P0 staging + xlds visible

  // ---------------- P1: E = exp2(C2 * enc_proj) in place (own chunks) ----------
  {
    float* Er = &E[(u >> 2) * EST + 32 * (u & 3)];
    #pragma unroll
    for (int i = 0; i < 8; ++i) {
      float4 ev = *(const float4*)(Er + 4 * i);
      ev.x = __builtin_amdgcn_exp2f(ev.x * C2);
      ev.y = __builtin_amdgcn_exp2f(ev.y * C2);
      ev.z = __builtin_amdgcn_exp2f(ev.z * C2);
      ev.w = __builtin_amdgcn_exp2f(ev.w * C2);
      *(float4*)(Er + 4 * i) = ev;
    }
  }
  // prologue Apre: zpart = h0 @ Wr (h0 from global; hbuf untouched -> no race)
  {
    float hA0 = h0[(size_t)b * HH + 32 * kq + (lane & 31)];
    float2 zac = {0.f, 0.f};
    #pragma unroll
    for (int i = 0; i < 32; ++i) {
      float2 wv = *(const float2*)(wrp + (size_t)i * 512);
      float hi = rdlane(hA0, i);
      zac.x += hi * wv.x;
      zac.y += hi * wv.y;
    }
    *(float2*)(&zpart[kq * 512 + 2 * cs2]) = zac;
  }
  __syncthreads();   // E final + zpart(h0) visible

  float* outb = out + (size_t)b * TT * TT;

  // ---------------- step loop: 2 barriers ----------------
  #pragma unroll 1
  for (int step = 0; step < TT; ++step) {
    // Wr batch A (rows 0..15): issue early, consumed in Apre after W1
    float2 wstA[16];
    #pragma unroll
    for (int i = 0; i < 16; ++i)
      wstA[i] = *(const float2*)(wrp + (size_t)i * 512);

    // ==== R window ====
    if (step > 0) {
      if (w < 4) {
        // ---- argmax path (critical): reduce -> mx -> ballot -> ptr -> gates ----
        float4 sc = {0.f, 0.f, 0.f, 0.f};
        #pragma unroll
        for (int q = 0; q < 16; ++q) {
          const float4 v = *(const float4*)(&scp[q * SCPS + 4 * lane]);
          sc.x += v.x; sc.y += v.y; sc.z += v.z; sc.w += v.w;
        }
        float m4 = fmaxf(fmaxf(sc.x, sc.y), fmaxf(sc.z, sc.w));
        int ttl = (sc.x == m4) ? 0 : (sc.y == m4) ? 1 : (sc.z == m4) ? 2 : 3;
        float mx = wave_max64(m4);
        unsigned long long bal = __ballot(m4 == mx);
        int ls  = __ffsll(bal) - 1;            // first-max lane = lowest t block
        int tc  = 4 * lane + ttl;
        int tts = __builtin_amdgcn_readlane(tc, ls);   // wave-uniform winner t
        const float2 pp = *(const float2*)(&xlds[2 * tts]);  // uniform broadcast
        ptr0 = pp.x;
        ptr1 = pp.y;
      } else if (w == 4) {
        // ---- softmax path (off critical, de-replicated to one wave) ----
        float4 sc = {0.f, 0.f, 0.f, 0.f};
        #pragma unroll
        for (int q = 0; q < 16; ++q) {
          const float4 v = *(const float4*)(&scp[q * SCPS + 4 * lane]);
          sc.x += v.x; sc.y += v.y; sc.z += v.z; sc.w += v.w;
        }
        sc.x += svr; sc.y += svr; sc.z += svr; sc.w += svr;
        float p0 = __builtin_amdgcn_exp2f((sc.x - 12.0f) * L2E);
        float p1 = __builtin_amdgcn_exp2f((sc.y - 12.0f) * L2E);
        float p2 = __builtin_amdgcn_exp2f((sc.z - 12.0f) * L2E);
        float p3 = __builtin_amdgcn_exp2f((sc.w - 12.0f) * L2E);
        float ws4 = wave_sum64((p0 + p1) + (p2 + p3));
        float rs = __builtin_amdgcn_rcpf(ws4);
        float4 po = {p0 * rs, p1 * rs, p2 * rs, p3 * rs};
        *(float4*)(&outb[(size_t)(step - 1) * TT + 4 * lane]) = po;
      }
    }
    if ((lane & 32) == 0 && w < 4) {   // gates: unit m=32w+lane, all 4 gates
      float z0 = bbg[0] + ptr0 * wkA[0] + ptr1 * wkB[0];
      float z1 = bbg[1] + ptr0 * wkA[1] + ptr1 * wkB[1];
      float z2 = bbg[2] + ptr0 * wkA[2] + ptr1 * wkB[2];
      float z3 = bbg[3] + ptr0 * wkA[3] + ptr1 * wkB[3];
      #pragma unroll
      for (int q = 0; q < 4; ++q) {
        z0 += zpart[q * 512 + 0 * HH + m];
        z1 += zpart[q * 512 + 1 * HH + m];
        z2 += zpart[q * 512 + 2 * HH + m];
        z3 += zpart[q * 512 + 3 * HH + m];
      }
      float ig = fast_sigmoid(z0);
      float fg = fast_sigmoid(z1);
      float gg = fast_tanh(z2);
      float og = fast_sigmoid(z3);
      c = fg * c + ig * gg;
      hbuf[m] = og * fast_tanh(c);
    }
    __syncthreads();                 // (W1) h_step visible

    // Wr batch B (rows 16..31): issue now, consumed ~200cy later
    float2 wstB[16];
    #pragma unroll
    for (int i = 0; i < 16; ++i)
      wstB[i] = *(const float2*)(wrp + (size_t)(16 + i) * 512);

    // ==== fat window: C (u_k octet) -> Apre -> D ====
    float Uk;
    {
      float cp = 0.0f;
      #pragma unroll
      for (int ii = 0; ii < 4; ++ii) {
        const float4 hv = *(const float4*)(hbuf + 4 * jq + 32 * ii);
        cp += hv.x * w2loc[4 * ii + 0];
        cp += hv.y * w2loc[4 * ii + 1];
        cp += hv.z * w2loc[4 * ii + 2];
        cp += hv.w * w2loc[4 * ii + 3];
      }
      float csum = cp;
      csum += dpp_mv<0x128>(csum);     // row_ror:8 == xor8 within the 16-row
      csum += __shfl_xor(csum, 16);
      csum += __shfl_xor(csum, 32);
      Uk = __builtin_amdgcn_exp2f(csum * C2);
    }
    // Apre: zpart = h_step @ Wr; h via 1 ds_read_b32 + rdlane broadcast
    {
      float hv1 = hbuf[32 * kq + (lane & 31)];
      float2 zac = {0.f, 0.f};
      #pragma unroll
      for (int i = 0; i < 16; ++i) {
        float hi = rdlane(hv1, i);
        zac.x += hi * wstA[i].x;
        zac.y += hi * wstA[i].y;
      }
      #pragma unroll
      for (int i = 0; i < 16; ++i) {
        float hi = rdlane(hv1, 16 + i);
        zac.x += hi * wstB[i].x;
        zac.y += hi * wstB[i].y;
      }
      *(float2*)(&zpart[kq * 512 + 2 * cs2]) = zac;
    }
    // D: wave w, k in [8w,+8); lane owns t in {lane,64+,128+,192+}
    {
      float uL[8], vL[8];
      #pragma unroll
      for (int i = 0; i < 8; ++i) uL[i] = rdlane(Uk, i);
      #pragma unroll
      for (int i = 0; i < 8; ++i) vL[i] = rdlane(v2r, i);
      #pragma unroll
      for (int tt = 0; tt < 4; ++tt) {
        const float* Er = &E[(64 * tt + lane) * EST + 8 * w];
        float4 e0 = *(const float4*)(Er + 0);
        float4 e1 = *(const float4*)(Er + 4);
        float a0 = 0.0f, a1 = 0.0f;
        float t0, t1, n;
        t0 = fmaf(e0.x, uL[0], 1.0f); t1 = fmaf(e0.y, uL[1], 1.0f);
        n  = fmaf(vL[1], t0, vL[0] * t1);
        a0 = fmaf(n, __builtin_amdgcn_rcpf(t0 * t1), a0);
        t0 = fmaf(e0.z, uL[2], 1.0f); t1 = fmaf(e0.w, uL[3], 1.0f);
        n  = fmaf(vL[3], t0, vL[2] * t1);
        a1 = fmaf(n, __builtin_amdgcn_rcpf(t0 * t1), a1);
        t0 = fmaf(e1.x, uL[4], 1.0f); t1 = fmaf(e1.y, uL[5], 1.0f);
        n  = fmaf(vL[5], t0, vL[4] * t1);
        a0 = fmaf(n, __builtin_amdgcn_rcpf(t0 * t1), a0);
        t0 = fmaf(e1.z, uL[6], 1.0f); t1 = fmaf(e1.w, uL[7], 1.0f);
        n  = fmaf(vL[7], t0, vL[6] * t1);
        a1 = fmaf(n, __builtin_amdgcn_rcpf(t0 * t1), a1);
        scp[w * SCPS + 64 * tt + lane] = a0 + a1;
      }
    }
    __syncthreads();                 // (W3) scp + zpart visible
  }

  // ---------------- peel: reduce + store final row (step 255) ----------------
  if (w == 4) {
    float4 sc = {0.f, 0.f, 0.f, 0.f};
    #pragma unroll
    for (int q = 0; q < 16; ++q) {
      const float4 v = *(const float4*)(&scp[q * SCPS + 4 * lane]);
      sc.x += v.x; sc.y += v.y; sc.z += v.z; sc.w += v.w;
    }
    sc.x += svr; sc.y += svr; sc.z += svr; sc.w += svr;
    float p0 = __builtin_amdgcn_exp2f((sc.x - 12.0f) * L2E);
    float p1 = __builtin_amdgcn_exp2f((sc.y - 12.0f) * L2E);
    float p2 = __builtin_amdgcn_exp2f((sc.z - 12.0f) * L2E);
    float p3 = __builtin_amdgcn_exp2f((sc.w - 12.0f) * L2E);
    float ws4 = wave_sum64((p0 + p1) + (p2 + p3));
    float rs = __builtin_amdgcn_rcpf(ws4);
    float4 po = {p0 * rs, p1 * rs, p2 * rs, p3 * rs};
    *(float4*)(&outb[(size_t)255 * TT + 4 * lane]) = po;
  }
}

extern "C" void kernel_launch(void* const* d_in, const int* in_sizes, int n_in,
                              void* d_out, int out_size, void* d_ws, size_t ws_size,
                              hipStream_t stream) {
  (void)in_sizes; (void)n_in; (void)d_ws; (void)ws_size; (void)out_size;
  const float* x    = (const float*)d_in[0];
  const float* enc  = (const float*)d_in[1];
  const float* h0   = (const float*)d_in[2];
  const float* c0   = (const float*)d_in[3];
  const float* W1   = (const float*)d_in[4];
  const float* W2   = (const float*)d_in[5];
  const float* V    = (const float*)d_in[6];
  const float* Wk   = (const float*)d_in[7];
  const float* Wr   = (const float*)d_in[8];
  const float* bias = (const float*)d_in[9];
  float* out = (float*)d_out;

  decoder_kernel<<<64, 1024, 0, stream>>>(x, enc, h0, c0, W1, W2, V, Wk, Wr, bias, out);
}

// Round 8
// 766.045 us; speedup vs baseline: 1.1879x; 1.1879x over previous
//
#include <hip/hip_runtime.h>
#include <cstddef>

#define TT 256
#define HH 128
#define EST 132    // E row stride: b128 reads land 8 dwords on every bank = balanced
#define SCPS 260   // scp row stride: 16B-aligned rows, banks balanced

typedef float f2 __attribute__((ext_vector_type(2)));
__device__ __forceinline__ f2 mkf2(float a, float b) { f2 r; r.x = a; r.y = b; return r; }
__device__ __forceinline__ f2 pkfma(f2 a, f2 b, f2 c) { return __builtin_elementwise_fma(a, b, c); }

__device__ __forceinline__ float rdlane(float v, int l) {
  return __int_as_float(__builtin_amdgcn_readlane(__float_as_int(v), l));
}
// DPP lane moves (VALU pipe; replaces ds_swizzle on LDS pipe). R6-verified.
template<int CTRL>
__device__ __forceinline__ float dpp_mv(float x) {
  return __int_as_float(
      __builtin_amdgcn_mov_dpp(__float_as_int(x), CTRL, 0xF, 0xF, true));
}
// quad_perm [1,0,3,2]=0xB1, [2,3,0,1]=0x4E, row_ror:4=0x124, row_ror:8=0x128
__device__ __forceinline__ float wave_max64(float x) {
  x = fmaxf(x, dpp_mv<0xB1>(x));
  x = fmaxf(x, dpp_mv<0x4E>(x));
  x = fmaxf(x, dpp_mv<0x124>(x));
  x = fmaxf(x, dpp_mv<0x128>(x));
  x = fmaxf(x, __shfl_xor(x, 16));
  x = fmaxf(x, __shfl_xor(x, 32));
  return x;
}
__device__ __forceinline__ float wave_sum64(float x) {
  x += dpp_mv<0xB1>(x);
  x += dpp_mv<0x4E>(x);
  x += dpp_mv<0x124>(x);
  x += dpp_mv<0x128>(x);
  x += __shfl_xor(x, 16);
  x += __shfl_xor(x, 32);
  return x;
}
__device__ __forceinline__ float fast_sigmoid(float x) {
  const float L2E = 1.4426950408889634f;
  float y = __builtin_amdgcn_exp2f(-x * L2E);
  return __builtin_amdgcn_rcpf(1.0f + y);
}
__device__ __forceinline__ float fast_tanh(float x) {
  const float C2 = 2.8853900817779268f;   // 2*log2(e)
  float y = __builtin_amdgcn_exp2f(x * C2);
  return 1.0f - 2.0f * __builtin_amdgcn_rcpf(1.0f + y);
}

// One workgroup per batch element; 512 threads = 8 waves (2/SIMD).
// Ledger: R0=752 | R1/R7 4w-SIMD=830/850 (never helps) | R2 ds_add=1222 |
// R4 reorder=flat | R5 pk+bad-h-read=793 (conflict tax masked pk) | R6 DPP=flat
// with +7.3M free conflicts (LDS slack proven).
// R8 = R0 structure + CLEAN instruction diet (the one untested axis: VALU issue
// is ~58% of active-CU cycles):
//  (1) pk-fma (v_pk_fma_f32) at P0/C/Apre/D -- R5's exact verified numerics,
//      WITHOUT R5's conflict-causing h-read change (broadcast b128 h kept).
//  (2) DPP reduce trees (R6-verified bit-exact).
//  (3) zpart loads hoisted to top of R-window: LDS in-order return hides their
//      latency behind the argmax scp reads (critical-path trim at gates entry).
// Lessons: no LDS atomics in loop (R2); no lane-strided b64 of hbuf (R5);
// occupancy/reorder/cross-lane are not the constraint (R1/R4/R6/R7).
__global__ __attribute__((amdgpu_flat_work_group_size(512, 512),
                          amdgpu_waves_per_eu(2, 2)))
void decoder_kernel(const float* __restrict__ x,
                    const float* __restrict__ enc_output,
                    const float* __restrict__ h0,
                    const float* __restrict__ c0,
                    const float* __restrict__ W1,
                    const float* __restrict__ W2,
                    const float* __restrict__ V,
                    const float* __restrict__ Wk,
                    const float* __restrict__ Wr,
                    const float* __restrict__ bias,
                    float* __restrict__ out)
{
  __shared__ float E[TT * EST];      // 135168 B : exp2(C2 * enc_proj)
  __shared__ float zpart[4 * 512];   // 8192 B   : h@Wr k-quarter partials
  __shared__ float scp[8 * SCPS];    // 8320 B   : phase-D partials [kgroup][t]
  __shared__ float hbuf[HH];         // 512 B
  __shared__ float xlds[2 * TT];     // 2048 B   : x pairs (ptr lookup)
  // total 154240 B <= 160 KiB

  const int u    = threadIdx.x;
  const int b    = blockIdx.x;
  const int lane = u & 63;
  const int w    = u >> 6;           // wave 0..7 (owns k in [16w,16w+16) for C/D)
  const float C2  = 2.8853900817779268f;
  const float L2E = 1.4426950408889634f;
  const f2 one2 = {1.0f, 1.0f};

  // ---------------- P0: enc_proj = enc_output[b] @ W1 -> E (raw) ----------------
  {
    const float* encb = enc_output + (size_t)b * TT * HH;
    const int tsub = u >> 4;
    const int ks   = (u & 15) * 8;
    for (int p = 0; p < 8; ++p) {
      const int tt = p * 32 + tsub;
      f2 a0l = {0.f, 0.f}, a0h = {0.f, 0.f};
      f2 a1l = {0.f, 0.f}, a1h = {0.f, 0.f};
      const float4* er4 = (const float4*)(encb + tt * HH);
      for (int j4 = 0; j4 < 32; ++j4) {
        const float4 ev = er4[j4];
        const float* w1p = W1 + (j4 * 4) * HH + ks;
        float4 wa, wb;
        f2 s;
        wa = *(const float4*)(w1p + 0 * HH); wb = *(const float4*)(w1p + 0 * HH + 4);
        s = mkf2(ev.x, ev.x);
        a0l = pkfma(s, mkf2(wa.x, wa.y), a0l); a0h = pkfma(s, mkf2(wa.z, wa.w), a0h);
        a1l = pkfma(s, mkf2(wb.x, wb.y), a1l); a1h = pkfma(s, mkf2(wb.z, wb.w), a1h);
        wa = *(const float4*)(w1p + 1 * HH); wb = *(const float4*)(w1p + 1 * HH + 4);
        s = mkf2(ev.y, ev.y);
        a0l = pkfma(s, mkf2(wa.x, wa.y), a0l); a0h = pkfma(s, mkf2(wa.z, wa.w), a0h);
        a1l = pkfma(s, mkf2(wb.x, wb.y), a1l); a1h = pkfma(s, mkf2(wb.z, wb.w), a1h);
        wa = *(const float4*)(w1p + 2 * HH); wb = *(const float4*)(w1p + 2 * HH + 4);
        s = mkf2(ev.z, ev.z);
        a0l = pkfma(s, mkf2(wa.x, wa.y), a0l); a0h = pkfma(s, mkf2(wa.z, wa.w), a0h);
        a1l = pkfma(s, mkf2(wb.x, wb.y), a1l); a1h = pkfma(s, mkf2(wb.z, wb.w), a1h);
        wa = *(const float4*)(w1p + 3 * HH); wb = *(const float4*)(w1p + 3 * HH + 4);
        s = mkf2(ev.w, ev.w);
        a0l = pkfma(s, mkf2(wa.x, wa.y), a0l); a0h = pkfma(s, mkf2(wa.z, wa.w), a0h);
        a1l = pkfma(s, mkf2(wb.x, wb.y), a1l); a1h = pkfma(s, mkf2(wb.z, wb.w), a1h);
      }
      float4 o0 = {a0l.x, a0l.y, a0h.x, a0h.y};
      float4 o1 = {a1l.x, a1l.y, a1h.x, a1h.y};
      *(float4*)(&E[tt * EST + ks])     = o0;
      *(float4*)(&E[tt * EST + ks + 4]) = o1;
    }
    xlds[u] = x[b * (TT * 2) + u];   // 512 threads cover all 512 floats
  }

  // ---------------- persistent registers ----------------
  // Apre: thread (kq = u>>7, cs = u&127) owns cols 4cs..4cs+3, k in [32kq,+32)
  const int kq = u >> 7;             // wave-uniform (w>>1)
  const int cs = u & 127;
  float4 wr4[32];
  #pragma unroll
  for (int i = 0; i < 32; ++i)
    wr4[i] = *(const float4*)(Wr + (32 * kq + i) * 512 + 4 * cs);
  // Gates: lanes 0..31 of waves 0..3 own unit m = 32w+lane (SIMD-balanced)
  const int m = 32 * (w & 3) + (lane & 31);
  float wkA[4], wkB[4], bbg[4];
  #pragma unroll
  for (int gg = 0; gg < 4; ++gg) {
    wkA[gg] = Wk[gg * HH + m];
    wkB[gg] = Wk[512 + gg * HH + m];
    bbg[gg] = bias[gg * HH + m];
  }
  float c = c0[b * HH + m];
  // Phase C (wave-local): lane -> kk = lane&15, jq = lane>>4
  const int kk = lane & 15;
  const int jq = lane >> 4;
  f2 w2f2[16];                       // {W2[32jq+2i][col], W2[32jq+2i+1][col]}
  #pragma unroll
  for (int i = 0; i < 16; ++i)
    w2f2[i] = mkf2(W2[(32 * jq + 2 * i) * HH + 16 * w + kk],
                   W2[(32 * jq + 2 * i + 1) * HH + 16 * w + kk]);
  // Phase D: v2 for k = 16w+i via loop-invariant readlane
  const float v2r = -2.0f * V[16 * w + kk];
  float vL[16];
  #pragma unroll
  for (int i = 0; i < 16; ++i) vL[i] = rdlane(v2r, i);
  float ptr0 = 1.0f, ptr1 = 1.0f;
  float svr;
  {
    float v = V[lane] + V[64 + lane];
    svr = wave_sum64(v);
  }

  __syncthreads();   // P0 staging + xlds visible

  // ---------------- P1: E = exp2(C2 * enc_proj) in place (own chunks) ----------
  {
    float* Er = &E[(u >> 1) * EST + 64 * (u & 1)];
    #pragma unroll
    for (int i = 0; i < 16; ++i) {
      float4 ev = *(const float4*)(Er + 4 * i);
      ev.x = __builtin_amdgcn_exp2f(ev.x * C2);
      ev.y = __builtin_amdgcn_exp2f(ev.y * C2);
      ev.z = __builtin_amdgcn_exp2f(ev.z * C2);
      ev.w = __builtin_amdgcn_exp2f(ev.w * C2);
      *(float4*)(Er + 4 * i) = ev;
    }
  }
  // prologue Apre: zpart = h0 @ Wr (h0 from global; hbuf untouched -> no race)
  {
    float hA0 = h0[(size_t)b * HH + 32 * kq + (lane & 31)];
    f2 zacl = {0.f, 0.f}, zach = {0.f, 0.f};
    #pragma unroll
    for (int i = 0; i < 32; ++i) {
      float hi = rdlane(hA0, i);
      f2 h2 = mkf2(hi, hi);
      zacl = pkfma(h2, mkf2(wr4[i].x, wr4[i].y), zacl);
      zach = pkfma(h2, mkf2(wr4[i].z, wr4[i].w), zach);
    }
    float4 zo = {zacl.x, zacl.y, zach.x, zach.y};
    *(float4*)(&zpart[kq * 512 + 4 * cs]) = zo;
  }
  __syncthreads();   // E final + zpart(h0) visible

  float* outb = out + (size_t)b * TT * TT;

  // ---------------- step loop: 2 barriers ----------------
  #pragma unroll 1
  for (int step = 0; step < TT; ++step) {
    // ==== R window ====
    // zpart prefetch for gate lanes: issued BEFORE the scp reduce so LDS
    // in-order return hides its latency behind the argmax reads.
    float zpv[16];
    const bool gate_lane = ((lane & 32) == 0 && w < 4);
    if (gate_lane) {
      #pragma unroll
      for (int q = 0; q < 4; ++q) {
        zpv[4 * q + 0] = zpart[q * 512 + 0 * HH + m];
        zpv[4 * q + 1] = zpart[q * 512 + 1 * HH + m];
        zpv[4 * q + 2] = zpart[q * 512 + 2 * HH + m];
        zpv[4 * q + 3] = zpart[q * 512 + 3 * HH + m];
      }
    }
    if (step > 0) {
      if (w < 4) {
        // ---- argmax path (critical): reduce -> mx -> ballot -> ptr -> gates ----
        float4 sc = {0.f, 0.f, 0.f, 0.f};
        #pragma unroll
        for (int q = 0; q < 8; ++q) {
          float4 v = *(const float4*)(&scp[q * SCPS + 4 * lane]);
          sc.x += v.x; sc.y += v.y; sc.z += v.z; sc.w += v.w;
        }
        float m4 = fmaxf(fmaxf(sc.x, sc.y), fmaxf(sc.z, sc.w));
        int ttl = (sc.x == m4) ? 0 : (sc.y == m4) ? 1 : (sc.z == m4) ? 2 : 3;
        float mx = wave_max64(m4);
        unsigned long long bal = __ballot(m4 == mx);
        int ls  = __ffsll(bal) - 1;            // first-max lane = lowest t block
        int tc  = 4 * lane + ttl;
        int tts = __builtin_amdgcn_readlane(tc, ls);   // wave-uniform winner t
        const float2 pp = *(const float2*)(&xlds[2 * tts]);  // uniform broadcast
        ptr0 = pp.x;
        ptr1 = pp.y;
      } else {
        // ---- softmax path (off critical): p -> ws -> out-row store ----
        float4 sc = {0.f, 0.f, 0.f, 0.f};
        #pragma unroll
        for (int q = 0; q < 8; ++q) {
          float4 v = *(const float4*)(&scp[q * SCPS + 4 * lane]);
          sc.x += v.x; sc.y += v.y; sc.z += v.z; sc.w += v.w;
        }
        sc.x += svr; sc.y += svr; sc.z += svr; sc.w += svr;
        float p0 = __builtin_amdgcn_exp2f((sc.x - 12.0f) * L2E);
        float p1 = __builtin_amdgcn_exp2f((sc.y - 12.0f) * L2E);
        float p2 = __builtin_amdgcn_exp2f((sc.z - 12.0f) * L2E);
        float p3 = __builtin_amdgcn_exp2f((sc.w - 12.0f) * L2E);
        float ws4 = wave_sum64((p0 + p1) + (p2 + p3));
        if ((lane >> 4) == (w - 4)) {          // wave 4+i writes t in [64i,64i+64)
          float rs = __builtin_amdgcn_rcpf(ws4);
          float4 po = {p0 * rs, p1 * rs, p2 * rs, p3 * rs};
          *(float4*)(&outb[(size_t)(step - 1) * TT + 4 * lane]) = po;
        }
      }
    }
    if (gate_lane) {                   // gates: unit m=32w+lane, all 4 gates
      float z0 = bbg[0] + ptr0 * wkA[0] + ptr1 * wkB[0];
      float z1 = bbg[1] + ptr0 * wkA[1] + ptr1 * wkB[1];
      float z2 = bbg[2] + ptr0 * wkA[2] + ptr1 * wkB[2];
      float z3 = bbg[3] + ptr0 * wkA[3] + ptr1 * wkB[3];
      z0 += (zpv[0] + zpv[4]) + (zpv[ 8] + zpv[12]);
      z1 += (zpv[1] + zpv[5]) + (zpv[ 9] + zpv[13]);
      z2 += (zpv[2] + zpv[6]) + (zpv[10] + zpv[14]);
      z3 += (zpv[3] + zpv[7]) + (zpv[11] + zpv[15]);
      float ig = fast_sigmoid(z0);
      float fg = fast_sigmoid(z1);
      float gg = fast_tanh(z2);
      float og = fast_sigmoid(z3);
      c = fg * c + ig * gg;
      hbuf[m] = og * fast_tanh(c);
    }
    __syncthreads();                 // (W1) h_step visible

    // ==== fat window: C (u_k chain) -> Apre (independent, hides C) -> D ====
    float Uk;
    {
      f2 cpv = {0.f, 0.f};
      const float4* h4 = (const float4*)(hbuf + 32 * jq);
      #pragma unroll
      for (int i4 = 0; i4 < 8; ++i4) {
        float4 hv = h4[i4];
        cpv = pkfma(mkf2(hv.x, hv.y), w2f2[2 * i4],     cpv);
        cpv = pkfma(mkf2(hv.z, hv.w), w2f2[2 * i4 + 1], cpv);
      }
      float csum = cpv.x + cpv.y;
      csum += __shfl_xor(csum, 16);
      csum += __shfl_xor(csum, 32);
      Uk = __builtin_amdgcn_exp2f(csum * C2);
    }
    // Apre: zpart = h_step @ Wr; h via broadcast b128 reads (kq wave-uniform)
    {
      const float4* h4 = (const float4*)(hbuf + 32 * kq);
      f2 zacl = {0.f, 0.f}, zach = {0.f, 0.f};
      #pragma unroll
      for (int i4 = 0; i4 < 8; ++i4) {
        float4 hv = h4[i4];
        f2 hx = mkf2(hv.x, hv.x), hy = mkf2(hv.y, hv.y);
        f2 hz = mkf2(hv.z, hv.z), hw = mkf2(hv.w, hv.w);
        zacl = pkfma(hx, mkf2(wr4[4 * i4 + 0].x, wr4[4 * i4 + 0].y), zacl);
        zach = pkfma(hx, mkf2(wr4[4 * i4 + 0].z, wr4[4 * i4 + 0].w), zach);
        zacl = pkfma(hy, mkf2(wr4[4 * i4 + 1].x, wr4[4 * i4 + 1].y), zacl);
        zach = pkfma(hy, mkf2(wr4[4 * i4 + 1].z, wr4[4 * i4 + 1].w), zach);
        zacl = pkfma(hz, mkf2(wr4[4 * i4 + 2].x, wr4[4 * i4 + 2].y), zacl);
        zach = pkfma(hz, mkf2(wr4[4 * i4 + 2].z, wr4[4 * i4 + 2].w), zach);
        zacl = pkfma(hw, mkf2(wr4[4 * i4 + 3].x, wr4[4 * i4 + 3].y), zacl);
        zach = pkfma(hw, mkf2(wr4[4 * i4 + 3].z, wr4[4 * i4 + 3].w), zach);
      }
      float4 zo = {zacl.x, zacl.y, zach.x, zach.y};
      *(float4*)(&zpart[kq * 512 + 4 * cs]) = zo;
    }
    // D: wave w, k in [16w,+16); lane owns t in {lane,64+,128+,192+}
    {
      float uL[16];
      #pragma unroll
      for (int i = 0; i < 16; ++i) uL[i] = rdlane(Uk, i);
      f2 uf2[8];
      #pragma unroll
      for (int j = 0; j < 8; ++j) uf2[j] = mkf2(uL[2 * j], uL[2 * j + 1]);
      #pragma unroll
      for (int tt = 0; tt < 4; ++tt) {
        const float* Er = &E[(64 * tt + lane) * EST + 16 * w];
        float4 e0 = *(const float4*)(Er + 0);
        float4 e1 = *(const float4*)(Er + 4);
        float4 e2 = *(const float4*)(Er + 8);
        float4 e3 = *(const float4*)(Er + 12);
        float a0 = 0.0f, a1 = 0.0f;
        f2 tp;
        float n;
        tp = pkfma(mkf2(e0.x, e0.y), uf2[0], one2);
        n  = fmaf(vL[ 1], tp.x, vL[ 0] * tp.y);
        a0 = fmaf(n, __builtin_amdgcn_rcpf(tp.x * tp.y), a0);
        tp = pkfma(mkf2(e0.z, e0.w), uf2[1], one2);
        n  = fmaf(vL[ 3], tp.x, vL[ 2] * tp.y);
        a1 = fmaf(n, __builtin_amdgcn_rcpf(tp.x * tp.y), a1);
        tp = pkfma(mkf2(e1.x, e1.y), uf2[2], one2);
        n  = fmaf(vL[ 5], tp.x, vL[ 4] * tp.y);
        a0 = fmaf(n, __builtin_amdgcn_rcpf(tp.x * tp.y), a0);
        tp = pkfma(mkf2(e1.z, e1.w), uf2[3], one2);
        n  = fmaf(vL[ 7], tp.x, vL[ 6] * tp.y);
        a1 = fmaf(n, __builtin_amdgcn_rcpf(tp.x * tp.y), a1);
        tp = pkfma(mkf2(e2.x, e2.y), uf2[4], one2);
        n  = fmaf(vL[ 9], tp.x, vL[ 8] * tp.y);
        a0 = fmaf(n, __builtin_amdgcn_rcpf(tp.x * tp.y), a0);
        tp = pkfma(mkf2(e2.z, e2.w), uf2[5], one2);
        n  = fmaf(vL[11], tp.x, vL[10] * tp.y);
        a1 = fmaf(n, __builtin_amdgcn_rcpf(tp.x * tp.y), a1);
        tp = pkfma(mkf2(e3.x, e3.y), uf2[6], one2);
        n  = fmaf(vL[13], tp.x, vL[12] * tp.y);
        a0 = fmaf(n, __builtin_amdgcn_rcpf(tp.x * tp.y), a0);
        tp = pkfma(mkf2(e3.z, e3.w), uf2[7], one2);
        n  = fmaf(vL[15], tp.x, vL[14] * tp.y);
        a1 = fmaf(n, __builtin_amdgcn_rcpf(tp.x * tp.y), a1);
        scp[w * SCPS + 64 * tt + lane] = a0 + a1;
      }
    }
    __syncthreads();                 // (W3) scp + zpart visible
  }

  // ---------------- peel: reduce + store final row (step 255) ----------------
  if (w >= 4) {
    float4 sc = {0.f, 0.f, 0.f, 0.f};
    #pragma unroll
    for (int q = 0; q < 8; ++q) {
      float4 v = *(const float4*)(&scp[q * SCPS + 4 * lane]);
      sc.x += v.x; sc.y += v.y; sc.z += v.z; sc.w += v.w;
    }
    sc.x += svr; sc.y += svr; sc.z += svr; sc.w += svr;
    float p0 = __builtin_amdgcn_exp2f((sc.x - 12.0f) * L2E);
    float p1 = __builtin_amdgcn_exp2f((sc.y - 12.0f) * L2E);
    float p2 = __builtin_amdgcn_exp2f((sc.z - 12.0f) * L2E);
    float p3 = __builtin_amdgcn_exp2f((sc.w - 12.0f) * L2E);
    float ws4 = wave_sum64((p0 + p1) + (p2 + p3));
    if ((lane >> 4) == (w - 4)) {
      float rs = __builtin_amdgcn_rcpf(ws4);
      float4 po = {p0 * rs, p1 * rs, p2 * rs, p3 * rs};
      *(float4*)(&outb[(size_t)255 * TT + 4 * lane]) = po;
    }
  }
}

extern "C" void kernel_launch(void* const* d_in, const int* in_sizes, int n_in,
                              void* d_out, int out_size, void* d_ws, size_t ws_size,
                              hipStream_t stream) {
  (void)in_sizes; (void)n_in; (void)d_ws; (void)ws_size; (void)out_size;
  const float* x    = (const float*)d_in[0];
  const float* enc  = (const float*)d_in[1];
  const float* h0   = (const float*)d_in[2];
  const float* c0   = (const float*)d_in[3];
  const float* W1   = (const float*)d_in[4];
  const float* W2   = (const float*)d_in[5];
  const float* V    = (const float*)d_in[6];
  const float* Wk   = (const float*)d_in[7];
  const float* Wr   = (const float*)d_in[8];
  const float* bias = (const float*)d_in[9];
  float* out = (float*)d_out;

  decoder_kernel<<<64, 512, 0, stream>>>(x, enc, h0, c0, W1, W2, V, Wk, Wr, bias, out);
}